// Round 5
// baseline (195.587 us; speedup 1.0000x reference)
//
#include <hip/hip_runtime.h>

// SimpleEdgeModel round 5: identical structure to round 3b/4, but with the
// register budget actually raised via __launch_bounds__(256, 2) (2 waves/EU
// -> 256 VGPRs/lane).  Round 4 post-mortem showed amdgpu_waves_per_eu(2,2)
// was ignored: VGPR_Count stayed 128 and ~100 regs spilled (41 MB WRITE_SIZE,
// 78 MB FETCH_SIZE of scratch traffic).  Live demand is ~210 regs.
//
// out[b,i,j] = Wo.relu(W3^T.relu(W2^T.relu(g_j+bc1-g_i)+bc2)+bc3)+bo
// g = nodeMLP(x)@Wc1 (layer c1 linear -> folded per node).
//
// Edge: layer2 computes e2^T = W2^T · e1^T (A=weights streamed from L2,
// B=e1^T built in regs); layer3 computes e3^T = W3^T · e2^T (B=e2^T via
// per-wave-private LDS slots, b64 writes / b128 reads).  Per wave: 64 j-rows
// x 4 i-units; no barriers; bc2/bc3 folded into acc init.

typedef _Float16 half_t;
typedef __attribute__((ext_vector_type(2))) _Float16 f16x2;
typedef __attribute__((ext_vector_type(8))) _Float16 f16x8;
typedef __attribute__((ext_vector_type(4))) float f32x4;

// ws layout:
//   gh  : 1024*128 f16 @ 0        = f16(g)
//   gbh : 1024*128 f16 @ 262144   = f16(g + bc1)
//   W2T : 16384 f16    @ 524288   (frag-packed Wc2, A-operand order)
//   W3T : 16384 f16    @ 557056

// ---------------------------------------------------------------------------
// prep: blocks 0..255 node MLP (4 nodes/block); 256..271 weight frag pack.
// Frag (ks,nt), lane L=q*16+c, elem e  <-  Wsrc[32ks+8q+e][16nt+c].
// ---------------------------------------------------------------------------
__global__ __launch_bounds__(256) void prep_kernel(
    const float* __restrict__ x, const float* __restrict__ Wa, const float* __restrict__ ba,
    const float* __restrict__ Wb, const float* __restrict__ bb, const float* __restrict__ Wc1,
    const float* __restrict__ bc1, const float* __restrict__ Wc2, const float* __restrict__ Wc3,
    half_t* __restrict__ gh, half_t* __restrict__ gbh,
    half_t* __restrict__ W2T, half_t* __restrict__ W3T)
{
  const int t = threadIdx.x;
  if (blockIdx.x >= 256) {
    const int bid = blockIdx.x - 256;            // layer(1b) x ntile(3b)
    const int layer = bid >> 3, nt = bid & 7;
    const int ks = t >> 6, L = t & 63, q = L >> 4, cc = L & 15;
    const float* src = layer ? Wc3 : Wc2;
    half_t* dst = layer ? W3T : W2T;
    f16x8 v;
    #pragma unroll
    for (int e = 0; e < 8; e++)
      v[e] = (half_t)src[(32 * ks + 8 * q + e) * 128 + 16 * nt + cc];
    *(f16x8*)(dst + (ks * 8 + nt) * 512 + L * 8) = v;
    return;
  }
  __shared__ float sx[64 * 6];
  __shared__ float sh1[128 * 6];
  __shared__ float sh2[128 * 6];
  const int n0 = blockIdx.x * 4;
  const int col = t & 127, hf = t >> 7;

  sx[(t & 63) * 6 + (t >> 6)] = x[(n0 + (t >> 6)) * 64 + (t & 63)];
  __syncthreads();

  float a0 = ba[col], a1 = a0;
  #pragma unroll
  for (int cc = 0; cc < 64; cc++) {
    const float wv = Wa[cc * 128 + col];
    const float2 xv = *(const float2*)(sx + cc * 6 + hf * 2);
    a0 = fmaf(xv.x, wv, a0); a1 = fmaf(xv.y, wv, a1);
  }
  *(float2*)(sh1 + col * 6 + hf * 2) = make_float2(fmaxf(a0, 0.f), fmaxf(a1, 0.f));
  __syncthreads();

  float b0 = bb[col], b1 = b0;
  #pragma unroll
  for (int k = 0; k < 128; k++) {
    const float wv = Wb[k * 128 + col];
    const float2 hv = *(const float2*)(sh1 + k * 6 + hf * 2);
    b0 = fmaf(hv.x, wv, b0); b1 = fmaf(hv.y, wv, b1);
  }
  *(float2*)(sh2 + col * 6 + hf * 2) = make_float2(fmaxf(b0, 0.f), fmaxf(b1, 0.f));
  __syncthreads();

  float c0 = 0.f, c1 = 0.f;
  #pragma unroll
  for (int k = 0; k < 128; k++) {
    const float wv = Wc1[k * 128 + col];
    const float2 hv = *(const float2*)(sh2 + k * 6 + hf * 2);
    c0 = fmaf(hv.x, wv, c0); c1 = fmaf(hv.y, wv, c1);
  }
  const float bv = bc1[col];
  const int r0 = n0 + hf * 2;
  gh [(r0 + 0) * 128 + col] = (half_t)c0;
  gh [(r0 + 1) * 128 + col] = (half_t)c1;
  gbh[(r0 + 0) * 128 + col] = (half_t)(c0 + bv);
  gbh[(r0 + 1) * 128 + col] = (half_t)(c1 + bv);
}

// ---------------------------------------------------------------------------
// edge kernel. 512 blocks = b(1b) x jhalf(1b) x ichunk(7b, 4 i each).
// Wave w owns j-rows [jhalf*256 + w*64, +64).  LDS: 16KB/wave private.
// __launch_bounds__(256, 2): 2 waves/EU -> 256-VGPR budget (live demand ~210).
// ---------------------------------------------------------------------------
static __device__ inline f16x8 relu_sub8(f16x8 a, f16x8 b) {
  f16x8 d = a - b;
  const f16x8 z = {};
  return __builtin_elementwise_max(d, z);
}

__global__ __launch_bounds__(256, 2)
void edge_kernel(
    const half_t* __restrict__ gh, const half_t* __restrict__ gbh,
    const half_t* __restrict__ W2T, const half_t* __restrict__ W3T,
    const float* __restrict__ bc2, const float* __restrict__ bc3,
    const float* __restrict__ Wo, const float* __restrict__ bo,
    float* __restrict__ out)
{
  __shared__ half_t sE[4 * 16 * 512];            // 64 KB, 16 KB per wave
  const int t = threadIdx.x, lane = t & 63, w = t >> 6;
  const int c = lane & 15, q = lane >> 4;
  const int bid = blockIdx.x;
  const int b = bid >> 8, jq = (bid >> 7) & 1, ic = bid & 127;
  const int i0 = ic * 4;
  const int j0w = jq * 256 + w * 64;

  half_t* sEw = sE + w * (16 * 512);
  const float bo0 = bo[0];
  // LDS pack address (half units): slot q2 = (n2t&1)*2 + (q>>1), byte (q&1)*8
  const int packoff = (((q >> 1) * 16 + c) * 16 + (q & 1) * 8) / 2;  // n2t-even part
  const int rdoff = lane * 8;

  for (int u = 0; u < 4; u++) {
    const int i = i0 + u;
    // ---- g_i slices (f16, lane needs k in [32ks+8q, +8)) ----
    f16x8 gih[4];
    #pragma unroll
    for (int ks = 0; ks < 4; ks++)
      gih[ks] = *(const f16x8*)(gh + (size_t)(b * 512 + i) * 128 + ks * 32 + q * 8);

    // ---- layer 2: acc2[n2t][jt] init = bc2 (rows n2 = 16n2t+4q+r) ----
    f32x4 acc2[8][4];
    #pragma unroll
    for (int nt = 0; nt < 8; nt++) {
      const f32x4 bv = *(const f32x4*)(bc2 + nt * 16 + q * 4);
      #pragma unroll
      for (int jt = 0; jt < 4; jt++) acc2[nt][jt] = bv;
    }
    #pragma unroll 2
    for (int ks = 0; ks < 4; ks++) {
      f16x8 wf[8];
      #pragma unroll
      for (int nt = 0; nt < 8; nt++)
        wf[nt] = *(const f16x8*)(W2T + (ks * 8 + nt) * 512 + rdoff);
      f16x8 e1[4];
      #pragma unroll
      for (int jt = 0; jt < 4; jt++) {
        const f16x8 gj = *(const f16x8*)(gbh + (size_t)(b * 512 + j0w + jt * 16 + c) * 128 + ks * 32 + q * 8);
        e1[jt] = relu_sub8(gj, gih[ks]);
      }
      #pragma unroll
      for (int nt = 0; nt < 8; nt++)
        #pragma unroll
        for (int jt = 0; jt < 4; jt++)
          acc2[nt][jt] = __builtin_amdgcn_mfma_f32_16x16x32_f16(wf[nt], e1[jt], acc2[nt][jt], 0, 0, 0);
    }

    // ---- pack e2^T -> LDS in layer-3 B-frag order (b64 writes) ----
    #pragma unroll
    for (int nt = 0; nt < 8; nt++) {
      const int ks3 = nt >> 1;
      const int po = packoff + (nt & 1) * (2 * 16 * 16 / 2);   // q2 += 2 when nt odd
      #pragma unroll
      for (int jt = 0; jt < 4; jt++) {
        const f32x4 v = acc2[nt][jt];
        const float r0 = fmaxf(v[0], 0.f), r1 = fmaxf(v[1], 0.f);
        const float r2 = fmaxf(v[2], 0.f), r3 = fmaxf(v[3], 0.f);
        f16x2 h01, h23;
        h01[0] = (half_t)r0; h01[1] = (half_t)r1;
        h23[0] = (half_t)r2; h23[1] = (half_t)r3;
        uint2 uv;
        uv.x = __builtin_bit_cast(unsigned int, h01);
        uv.y = __builtin_bit_cast(unsigned int, h23);
        *(uint2*)(sEw + (jt * 4 + ks3) * 512 + po) = uv;
      }
    }

    // ---- layer 3: acc3[n3t][jt] init = bc3 ----
    f32x4 acc3[8][4];
    #pragma unroll
    for (int nt = 0; nt < 8; nt++) {
      const f32x4 bv = *(const f32x4*)(bc3 + nt * 16 + q * 4);
      #pragma unroll
      for (int jt = 0; jt < 4; jt++) acc3[nt][jt] = bv;
    }
    #pragma unroll 2
    for (int ks3 = 0; ks3 < 4; ks3++) {
      f16x8 wf[8];
      #pragma unroll
      for (int nt = 0; nt < 8; nt++)
        wf[nt] = *(const f16x8*)(W3T + (ks3 * 8 + nt) * 512 + rdoff);
      f16x8 be[4];
      #pragma unroll
      for (int jt = 0; jt < 4; jt++)
        be[jt] = *(const f16x8*)(sEw + (jt * 4 + ks3) * 512 + rdoff);
      #pragma unroll
      for (int nt = 0; nt < 8; nt++)
        #pragma unroll
        for (int jt = 0; jt < 4; jt++)
          acc3[nt][jt] = __builtin_amdgcn_mfma_f32_16x16x32_f16(wf[nt], be[jt], acc3[nt][jt], 0, 0, 0);
    }

    // ---- epilogue: p[jt] = sum_n3 relu(e3)*Wo, reduce over q, store ----
    float p[4] = {0.f, 0.f, 0.f, 0.f};
    #pragma unroll
    for (int nt = 0; nt < 8; nt++) {
      const f32x4 wv = *(const f32x4*)(Wo + nt * 16 + q * 4);
      #pragma unroll
      for (int jt = 0; jt < 4; jt++)
        #pragma unroll
        for (int r = 0; r < 4; r++)
          p[jt] = fmaf(fmaxf(acc3[nt][jt][r], 0.f), wv[r], p[jt]);
    }
    #pragma unroll
    for (int jt = 0; jt < 4; jt++) {
      p[jt] += __shfl_xor(p[jt], 16, 64);
      p[jt] += __shfl_xor(p[jt], 32, 64);
    }
    if (q == 0) {
      const size_t base = ((size_t)(b * 512 + i)) * 512 + j0w;
      #pragma unroll
      for (int jt = 0; jt < 4; jt++)
        out[base + jt * 16 + c] = p[jt] + bo0;
    }
  }
}

// ---------------------------------------------------------------------------
extern "C" void kernel_launch(void* const* d_in, const int* in_sizes, int n_in,
                              void* d_out, int out_size, void* d_ws, size_t ws_size,
                              hipStream_t stream)
{
  const float* x   = (const float*)d_in[0];
  const float* Wa  = (const float*)d_in[1];
  const float* ba  = (const float*)d_in[2];
  const float* Wb  = (const float*)d_in[3];
  const float* bb  = (const float*)d_in[4];
  const float* Wc1 = (const float*)d_in[5];
  const float* bc1 = (const float*)d_in[6];
  const float* Wc2 = (const float*)d_in[7];
  const float* bc2 = (const float*)d_in[8];
  const float* Wc3 = (const float*)d_in[9];
  const float* bc3 = (const float*)d_in[10];
  const float* Wo  = (const float*)d_in[11];
  const float* bo  = (const float*)d_in[12];
  float* out = (float*)d_out;

  char* ws = (char*)d_ws;
  half_t* gh  = (half_t*)ws;                      // 256 KB
  half_t* gbh = (half_t*)(ws + 262144);           // 256 KB
  half_t* W2T = (half_t*)(ws + 524288);           // 32 KB
  half_t* W3T = (half_t*)(ws + 557056);           // 32 KB

  prep_kernel<<<272, 256, 0, stream>>>(x, Wa, ba, Wb, bb, Wc1, bc1, Wc2, Wc3,
                                       gh, gbh, W2T, W3T);
  edge_kernel<<<512, 256, 0, stream>>>(gh, gbh, W2T, W3T, bc2, bc3, Wo, bo, out);
}

// Round 6
// 132.170 us; speedup vs baseline: 1.4798x; 1.4798x over previous
//
#include <hip/hip_runtime.h>

// SimpleEdgeModel round 6: fit the edge kernel in 128 VGPRs (no spills).
//
// R4/R5 lesson (measured twice): amdgpu_waves_per_eu(2,2) and
// __launch_bounds__(256,2) do NOT raise the backend's register target —
// VGPR_Count stayed 128 and ~100 regs spilled (41 MB WRITE / 78 MB FETCH of
// scratch traffic).  Fix: loop-reorder so peak live regs ~116 < 128.
//   - n-tile loop OUTERMOST, not unrolled: acc is 16 regs per nt, dies at
//     the LDS pack.  Persistent state is e1[4][4] (64) in layer 2 and
//     be[4][4] (64) in layer 3 — never both.
//   - biases/Wo applied at pack/epilogue time, not acc init (acc inits 0).
//
// out[b,i,j] = Wo.relu(W3^T.relu(W2^T.relu(g_j+bc1-g_i)+bc2)+bc3)+bo
// g = nodeMLP(x)@Wc1 (layer c1 linear -> folded per node).
// Layer2: e2^T = W2^T·e1^T (A=weights from L2, B=e1^T in regs); handoff of
// e2 C-layout -> layer-3 B-frags via per-wave-private LDS (b64 wr/b128 rd);
// Layer3: e3^T = W3^T·e2^T.  Per wave: 64 j-rows x 4 i-units; no barriers.

typedef _Float16 half_t;
typedef __attribute__((ext_vector_type(2))) _Float16 f16x2;
typedef __attribute__((ext_vector_type(8))) _Float16 f16x8;
typedef __attribute__((ext_vector_type(4))) float f32x4;

// ws layout:
//   gh  : 1024*128 f16 @ 0        = f16(g)
//   gbh : 1024*128 f16 @ 262144   = f16(g + bc1)
//   W2T : 16384 f16    @ 524288   (frag-packed Wc2, A-operand order)
//   W3T : 16384 f16    @ 557056

// ---------------------------------------------------------------------------
// prep: blocks 0..255 node MLP (4 nodes/block); 256..271 weight frag pack.
// Frag (ks,nt), lane L=q*16+c, elem e  <-  Wsrc[32ks+8q+e][16nt+c].
// ---------------------------------------------------------------------------
__global__ __launch_bounds__(256) void prep_kernel(
    const float* __restrict__ x, const float* __restrict__ Wa, const float* __restrict__ ba,
    const float* __restrict__ Wb, const float* __restrict__ bb, const float* __restrict__ Wc1,
    const float* __restrict__ bc1, const float* __restrict__ Wc2, const float* __restrict__ Wc3,
    half_t* __restrict__ gh, half_t* __restrict__ gbh,
    half_t* __restrict__ W2T, half_t* __restrict__ W3T)
{
  const int t = threadIdx.x;
  if (blockIdx.x >= 256) {
    const int bid = blockIdx.x - 256;            // layer(1b) x ntile(3b)
    const int layer = bid >> 3, nt = bid & 7;
    const int ks = t >> 6, L = t & 63, q = L >> 4, cc = L & 15;
    const float* src = layer ? Wc3 : Wc2;
    half_t* dst = layer ? W3T : W2T;
    f16x8 v;
    #pragma unroll
    for (int e = 0; e < 8; e++)
      v[e] = (half_t)src[(32 * ks + 8 * q + e) * 128 + 16 * nt + cc];
    *(f16x8*)(dst + (ks * 8 + nt) * 512 + L * 8) = v;
    return;
  }
  __shared__ float sx[64 * 6];
  __shared__ float sh1[128 * 6];
  __shared__ float sh2[128 * 6];
  const int n0 = blockIdx.x * 4;
  const int col = t & 127, hf = t >> 7;

  sx[(t & 63) * 6 + (t >> 6)] = x[(n0 + (t >> 6)) * 64 + (t & 63)];
  __syncthreads();

  float a0 = ba[col], a1 = a0;
  #pragma unroll
  for (int cc = 0; cc < 64; cc++) {
    const float wv = Wa[cc * 128 + col];
    const float2 xv = *(const float2*)(sx + cc * 6 + hf * 2);
    a0 = fmaf(xv.x, wv, a0); a1 = fmaf(xv.y, wv, a1);
  }
  *(float2*)(sh1 + col * 6 + hf * 2) = make_float2(fmaxf(a0, 0.f), fmaxf(a1, 0.f));
  __syncthreads();

  float b0 = bb[col], b1 = b0;
  #pragma unroll
  for (int k = 0; k < 128; k++) {
    const float wv = Wb[k * 128 + col];
    const float2 hv = *(const float2*)(sh1 + k * 6 + hf * 2);
    b0 = fmaf(hv.x, wv, b0); b1 = fmaf(hv.y, wv, b1);
  }
  *(float2*)(sh2 + col * 6 + hf * 2) = make_float2(fmaxf(b0, 0.f), fmaxf(b1, 0.f));
  __syncthreads();

  float c0 = 0.f, c1 = 0.f;
  #pragma unroll
  for (int k = 0; k < 128; k++) {
    const float wv = Wc1[k * 128 + col];
    const float2 hv = *(const float2*)(sh2 + k * 6 + hf * 2);
    c0 = fmaf(hv.x, wv, c0); c1 = fmaf(hv.y, wv, c1);
  }
  const float bv = bc1[col];
  const int r0 = n0 + hf * 2;
  gh [(r0 + 0) * 128 + col] = (half_t)c0;
  gh [(r0 + 1) * 128 + col] = (half_t)c1;
  gbh[(r0 + 0) * 128 + col] = (half_t)(c0 + bv);
  gbh[(r0 + 1) * 128 + col] = (half_t)(c1 + bv);
}

// ---------------------------------------------------------------------------
// edge kernel. 512 blocks = b(1b) x jhalf(1b) x ichunk(7b, 4 i each).
// Wave w owns j-rows [jhalf*256 + w*64, +64).  LDS: 16KB/wave private.
// ---------------------------------------------------------------------------
static __device__ inline f16x8 relu_sub8(f16x8 a, f16x8 b) {
  f16x8 d = a - b;
  const f16x8 z = {};
  return __builtin_elementwise_max(d, z);
}

__global__ __launch_bounds__(256)
void edge_kernel(
    const half_t* __restrict__ gh, const half_t* __restrict__ gbh,
    const half_t* __restrict__ W2T, const half_t* __restrict__ W3T,
    const float* __restrict__ bc2, const float* __restrict__ bc3,
    const float* __restrict__ Wo, const float* __restrict__ bo,
    float* __restrict__ out)
{
  __shared__ half_t sE[4 * 16 * 512];            // 64 KB, 16 KB per wave
  const int t = threadIdx.x, lane = t & 63, w = t >> 6;
  const int c = lane & 15, q = lane >> 4;
  const int bid = blockIdx.x;
  const int b = bid >> 8, jq = (bid >> 7) & 1, ic = bid & 127;
  const int i0 = ic * 4;
  const int j0w = jq * 256 + w * 64;

  half_t* sEw = sE + w * (16 * 512);
  const float bo0 = bo[0];
  // LDS pack address (halfs): ((q>>1)*16+c)*8 + (q&1)*4; +256 halfs when nt odd
  const int packoff = ((q >> 1) * 16 + c) * 8 + (q & 1) * 4;
  const int rdoff = lane * 8;

  for (int u = 0; u < 4; u++) {
    const int i = i0 + u;

    // ---- phase A: build e1[ks][jt] in regs (64 VGPRs) ----
    f16x8 e1[4][4];
    {
      f16x8 gih[4];
      #pragma unroll
      for (int ks = 0; ks < 4; ks++)
        gih[ks] = *(const f16x8*)(gh + (size_t)(b * 512 + i) * 128 + ks * 32 + q * 8);
      #pragma unroll
      for (int ks = 0; ks < 4; ks++)
        #pragma unroll
        for (int jt = 0; jt < 4; jt++) {
          const f16x8 gj = *(const f16x8*)(gbh + (size_t)(b * 512 + j0w + jt * 16 + c) * 128 + ks * 32 + q * 8);
          e1[ks][jt] = relu_sub8(gj, gih[ks]);
        }
    }

    // ---- phase B: layer 2, nt outermost (acc 16 regs, dies at pack) ----
    #pragma unroll 1
    for (int nt = 0; nt < 8; nt++) {
      f16x8 wf[4];
      #pragma unroll
      for (int ks = 0; ks < 4; ks++)
        wf[ks] = *(const f16x8*)(W2T + (ks * 8 + nt) * 512 + rdoff);
      f32x4 acc[4] = {};
      #pragma unroll
      for (int ks = 0; ks < 4; ks++)
        #pragma unroll
        for (int jt = 0; jt < 4; jt++)
          acc[jt] = __builtin_amdgcn_mfma_f32_16x16x32_f16(wf[ks], e1[ks][jt], acc[jt], 0, 0, 0);
      // pack e2 = relu(acc + bc2) -> LDS in layer-3 B-frag order (b64 writes)
      const f32x4 b2 = *(const f32x4*)(bc2 + nt * 16 + q * 4);
      const int po = ((nt >> 1) * 512) + packoff + (nt & 1) * 256;   // ks3 slot base
      #pragma unroll
      for (int jt = 0; jt < 4; jt++) {
        const f32x4 v = acc[jt];
        const float r0 = fmaxf(v[0] + b2[0], 0.f), r1 = fmaxf(v[1] + b2[1], 0.f);
        const float r2 = fmaxf(v[2] + b2[2], 0.f), r3 = fmaxf(v[3] + b2[3], 0.f);
        f16x2 h01, h23;
        h01[0] = (half_t)r0; h01[1] = (half_t)r1;
        h23[0] = (half_t)r2; h23[1] = (half_t)r3;
        uint2 uv;
        uv.x = __builtin_bit_cast(unsigned int, h01);
        uv.y = __builtin_bit_cast(unsigned int, h23);
        *(uint2*)(sEw + jt * 2048 + po) = uv;    // (jt*4+ks3)*512 = jt*2048 + ks3*512
      }
    }

    // ---- phase C: layer 3; be[ks3][jt] from LDS (64 regs, e1 dead) ----
    f16x8 be[4][4];
    #pragma unroll
    for (int ks3 = 0; ks3 < 4; ks3++)
      #pragma unroll
      for (int jt = 0; jt < 4; jt++)
        be[ks3][jt] = *(const f16x8*)(sEw + (jt * 4 + ks3) * 512 + rdoff);

    float p[4] = {0.f, 0.f, 0.f, 0.f};
    #pragma unroll 1
    for (int nt = 0; nt < 8; nt++) {
      f16x8 wf[4];
      #pragma unroll
      for (int ks3 = 0; ks3 < 4; ks3++)
        wf[ks3] = *(const f16x8*)(W3T + (ks3 * 8 + nt) * 512 + rdoff);
      f32x4 acc[4] = {};
      #pragma unroll
      for (int ks3 = 0; ks3 < 4; ks3++)
        #pragma unroll
        for (int jt = 0; jt < 4; jt++)
          acc[jt] = __builtin_amdgcn_mfma_f32_16x16x32_f16(wf[ks3], be[ks3][jt], acc[jt], 0, 0, 0);
      const f32x4 b3 = *(const f32x4*)(bc3 + nt * 16 + q * 4);
      const f32x4 wo = *(const f32x4*)(Wo  + nt * 16 + q * 4);
      #pragma unroll
      for (int jt = 0; jt < 4; jt++)
        #pragma unroll
        for (int r = 0; r < 4; r++)
          p[jt] = fmaf(fmaxf(acc[jt][r] + b3[r], 0.f), wo[r], p[jt]);
    }

    // ---- epilogue: reduce over q (rows n3 split across q), store ----
    #pragma unroll
    for (int jt = 0; jt < 4; jt++) {
      p[jt] += __shfl_xor(p[jt], 16, 64);
      p[jt] += __shfl_xor(p[jt], 32, 64);
    }
    if (q == 0) {
      const size_t base = ((size_t)(b * 512 + i)) * 512 + j0w;
      #pragma unroll
      for (int jt = 0; jt < 4; jt++)
        out[base + jt * 16 + c] = p[jt] + bo0;
    }
  }
}

// ---------------------------------------------------------------------------
extern "C" void kernel_launch(void* const* d_in, const int* in_sizes, int n_in,
                              void* d_out, int out_size, void* d_ws, size_t ws_size,
                              hipStream_t stream)
{
  const float* x   = (const float*)d_in[0];
  const float* Wa  = (const float*)d_in[1];
  const float* ba  = (const float*)d_in[2];
  const float* Wb  = (const float*)d_in[3];
  const float* bb  = (const float*)d_in[4];
  const float* Wc1 = (const float*)d_in[5];
  const float* bc1 = (const float*)d_in[6];
  const float* Wc2 = (const float*)d_in[7];
  const float* bc2 = (const float*)d_in[8];
  const float* Wc3 = (const float*)d_in[9];
  const float* bc3 = (const float*)d_in[10];
  const float* Wo  = (const float*)d_in[11];
  const float* bo  = (const float*)d_in[12];
  float* out = (float*)d_out;

  char* ws = (char*)d_ws;
  half_t* gh  = (half_t*)ws;                      // 256 KB
  half_t* gbh = (half_t*)(ws + 262144);           // 256 KB
  half_t* W2T = (half_t*)(ws + 524288);           // 32 KB
  half_t* W3T = (half_t*)(ws + 557056);           // 32 KB

  prep_kernel<<<272, 256, 0, stream>>>(x, Wa, ba, Wb, bb, Wc1, bc1, Wc2, Wc3,
                                       gh, gbh, W2T, W3T);
  edge_kernel<<<512, 256, 0, stream>>>(gh, gbh, W2T, W3T, bc2, bc3, Wo, bo, out);
}